// Round 2
// baseline (22513.657 us; speedup 1.0000x reference)
//
#include <hip/hip_runtime.h>
#include <hip/hip_bf16.h>

typedef short s8v __attribute__((ext_vector_type(8)));
typedef float f4v __attribute__((ext_vector_type(4)));

__device__ inline void bsplit(float v, __hip_bfloat16& h, __hip_bfloat16& l) {
    h = __float2bfloat16(v);
    l = __float2bfloat16(v - __bfloat162float(h));
}

// ---------------------------------------------------------------------------
// Direct 3x3 stride-2 pad-1 conv + BN + ReLU (fp32).
// ---------------------------------------------------------------------------
__global__ __launch_bounds__(256) void conv3x3_s2(
    const float* __restrict__ in, const float* __restrict__ w,
    const float* __restrict__ g, const float* __restrict__ bb,
    const float* __restrict__ bm, const float* __restrict__ bv,
    float* __restrict__ out, int Cin, int Cout, int Hin, int Win, int Hout, int Wout)
{
    extern __shared__ float wsh[];
    int co = blockIdx.y, b = blockIdx.z;
    int nW = Cin * 9;
    for (int i = threadIdx.x; i < nW; i += 256) wsh[i] = w[(long)co * nW + i];
    __syncthreads();
    int sp = blockIdx.x * 256 + threadIdx.x;
    int HW = Hout * Wout;
    if (sp >= HW) return;
    int oy = sp / Wout, ox = sp - oy * Wout;
    int iy0 = oy * 2 - 1, ix0 = ox * 2 - 1;
    const float* ib = in + (long)b * Cin * Hin * Win;
    float acc = 0.f;
    for (int ci = 0; ci < Cin; ci++) {
        const float* ip = ib + (long)ci * Hin * Win;
        const float* wp = wsh + ci * 9;
        #pragma unroll
        for (int ky = 0; ky < 3; ky++) {
            int y = iy0 + ky;
            if ((unsigned)y >= (unsigned)Hin) continue;
            const float* rp = ip + (long)y * Win;
            #pragma unroll
            for (int kx = 0; kx < 3; kx++) {
                int xx = ix0 + kx;
                if ((unsigned)xx >= (unsigned)Win) continue;
                acc += rp[xx] * wp[ky * 3 + kx];
            }
        }
    }
    float sc = g[co] * rsqrtf(bv[co] + 1e-5f);
    float val = (acc - bm[co]) * sc + bb[co];
    out[(long)(b * Cout + co) * HW + sp] = fmaxf(val, 0.f);
}

// ---------------------------------------------------------------------------
// Tiled transpose fp32 [z][K][N] -> bf16 hi/lo [z][N][K]
// ---------------------------------------------------------------------------
__global__ __launch_bounds__(256) void transpose_split(
    const float* __restrict__ src, __hip_bfloat16* __restrict__ dh,
    __hip_bfloat16* __restrict__ dl, int K, int N)
{
    __shared__ float tile[32][33];
    int z = blockIdx.z;
    long so = (long)z * K * N;
    int n0 = blockIdx.x * 32, k0 = blockIdx.y * 32;
    int tx = threadIdx.x & 31, ty = threadIdx.x >> 5;
    #pragma unroll
    for (int r = 0; r < 32; r += 8) {
        int k = k0 + ty + r, n = n0 + tx;
        tile[ty + r][tx] = (k < K && n < N) ? src[so + (long)k * N + n] : 0.f;
    }
    __syncthreads();
    #pragma unroll
    for (int r = 0; r < 32; r += 8) {
        int n = n0 + ty + r, k = k0 + tx;
        if (n < N && k < K) {
            __hip_bfloat16 h, l;
            bsplit(tile[tx][ty + r], h, l);
            dh[so + (long)n * K + k] = h;
            dl[so + (long)n * K + k] = l;
        }
    }
}

__global__ __launch_bounds__(256) void f32_split_k(
    const float* __restrict__ s, __hip_bfloat16* __restrict__ dh,
    __hip_bfloat16* __restrict__ dl, long n)
{
    long i = (long)blockIdx.x * 256 + threadIdx.x;
    if (i < n) { __hip_bfloat16 h, l; bsplit(s[i], h, l); dh[i] = h; dl[i] = l; }
}

__global__ __launch_bounds__(256) void bn_prep(
    const float* __restrict__ g, const float* __restrict__ b,
    const float* __restrict__ m, const float* __restrict__ v,
    float* __restrict__ sc, float* __restrict__ bs, int n)
{
    int i = blockIdx.x * 256 + threadIdx.x;
    if (i < n) {
        float s = g[i] * rsqrtf(v[i] + 1e-5f);
        sc[i] = s;
        bs[i] = b[i] - m[i] * s;
    }
}

__global__ __launch_bounds__(256) void cls_embed(
    const float* __restrict__ cls, const float* __restrict__ pos, float* __restrict__ x)
{
    int i = blockIdx.x * 256 + threadIdx.x;  // 32*768
    if (i >= 32 * 768) return;
    int b = i / 768, c = i - b * 768;
    x[(long)b * 197 * 768 + c] = cls[c] + pos[c];
}

// ---------------------------------------------------------------------------
// LayerNorm (unbiased var, eps on std) fp32 -> bf16 hi/lo
// ---------------------------------------------------------------------------
__global__ __launch_bounds__(256) void ln_fwd(
    const float* __restrict__ in, long rowStride,
    const float* __restrict__ a, const float* __restrict__ bb,
    __hip_bfloat16* __restrict__ oh, __hip_bfloat16* __restrict__ ol, int nrows)
{
    int row = blockIdx.x;
    if (row >= nrows) return;
    const float* p = in + (long)row * rowStride;
    int t = threadIdx.x;
    float v0 = p[t], v1 = p[t + 256], v2 = p[t + 512];
    float s = v0 + v1 + v2;
    float sq = v0 * v0 + v1 * v1 + v2 * v2;
    #pragma unroll
    for (int o = 32; o > 0; o >>= 1) { s += __shfl_xor(s, o); sq += __shfl_xor(sq, o); }
    __shared__ float red[8];
    int wv = t >> 6;
    if ((t & 63) == 0) { red[wv] = s; red[wv + 4] = sq; }
    __syncthreads();
    s = red[0] + red[1] + red[2] + red[3];
    sq = red[4] + red[5] + red[6] + red[7];
    float mu = s * (1.f / 768.f);
    float var = fmaxf((sq - 768.f * mu * mu) * (1.f / 767.f), 0.f);
    float inv = 1.f / (sqrtf(var) + 1e-4f);
    long ro = (long)row * 768;
    #pragma unroll
    for (int j = 0; j < 3; j++) {
        int c = t + j * 256;
        float vv = (j == 0) ? v0 : (j == 1) ? v1 : v2;
        float y = a[c] * ((vv - mu) * inv) + bb[c];
        __hip_bfloat16 h, l;
        bsplit(y, h, l);
        oh[ro + c] = h;
        ol[ro + c] = l;
    }
}

// ---------------------------------------------------------------------------
// Repack qkv fp32 [6304][2304] -> q,k hi/lo [bh][197][64]
// ---------------------------------------------------------------------------
__global__ __launch_bounds__(256) void repack_qk_f(
    const float* __restrict__ qkv,
    __hip_bfloat16* __restrict__ qh, __hip_bfloat16* __restrict__ ql,
    __hip_bfloat16* __restrict__ kh, __hip_bfloat16* __restrict__ kl)
{
    long idx = (long)blockIdx.x * 256 + threadIdx.x;
    const long half = 6304L * 768;
    if (idx >= 2 * half) return;
    int which = idx >= half;
    long r = idx - (long)which * half;
    int tok = (int)(r / 768), c = (int)(r - (long)tok * 768);
    int b = tok / 197, i = tok - b * 197;
    int h = c >> 6, d = c & 63;
    float val = qkv[(long)tok * 2304 + which * 768 + c];
    __hip_bfloat16 vh, vl;
    bsplit(val, vh, vl);
    long di = ((long)(b * 12 + h) * 197 + i) * 64 + d;
    if (which) { kh[di] = vh; kl[di] = vl; } else { qh[di] = vh; ql[di] = vl; }
}

// v -> vT hi/lo [bh][64][224] (pads zeroed)
__global__ __launch_bounds__(256) void repack_v_f(
    const float* __restrict__ qkv, __hip_bfloat16* __restrict__ vh,
    __hip_bfloat16* __restrict__ vl)
{
    int bh = blockIdx.y, j0 = blockIdx.x * 64;
    int b = bh / 12, h = bh - b * 12;
    __shared__ float tl[64][65];
    int tx = threadIdx.x & 63, ty4 = threadIdx.x >> 6;
    #pragma unroll
    for (int r = 0; r < 64; r += 4) {
        int j = j0 + ty4 + r;
        tl[ty4 + r][tx] = (j < 197)
            ? qkv[(long)(b * 197 + j) * 2304 + 1536 + h * 64 + tx] : 0.f;
    }
    __syncthreads();
    #pragma unroll
    for (int r = 0; r < 64; r += 4) {
        int d = ty4 + r, jl = tx, j = j0 + jl;
        if (j < 224) {
            __hip_bfloat16 hh, ll;
            bsplit(tl[jl][d], hh, ll);
            long di = ((long)bh * 64 + d) * 224 + j;
            vh[di] = hh; vl[di] = ll;
        }
    }
}

// ---------------------------------------------------------------------------
// Softmax on S fp32 [row][224] (valid 197); writes att hi/lo bf16 packed
// IN-PLACE into the same row (448 bf16 slots: [0,224)=hi, [224,448)=lo).
// ---------------------------------------------------------------------------
__global__ __launch_bounds__(256) void softmax_k(
    float* __restrict__ S, int nrows)
{
    int row = blockIdx.x * 4 + (threadIdx.x >> 6);
    if (row >= nrows) return;
    int lane = threadIdx.x & 63;
    float* sp = S + (long)row * 224;
    float v0 = sp[lane];
    float v1 = sp[lane + 64];
    float v2 = sp[lane + 128];
    int j3 = lane + 192;
    float v3 = (j3 < 197) ? sp[j3] : -1e30f;
    float mx = fmaxf(fmaxf(v0, v1), fmaxf(v2, v3));
    #pragma unroll
    for (int o = 32; o > 0; o >>= 1) mx = fmaxf(mx, __shfl_xor(mx, o));
    v0 = __expf(v0 - mx); v1 = __expf(v1 - mx); v2 = __expf(v2 - mx);
    v3 = (j3 < 197) ? __expf(v3 - mx) : 0.f;
    float s = v0 + v1 + v2 + v3;
    #pragma unroll
    for (int o = 32; o > 0; o >>= 1) s += __shfl_xor(s, o);
    float rs = 1.f / s;
    __hip_bfloat16* hp = (__hip_bfloat16*)sp;        // 448 slots
    __hip_bfloat16* lp = hp + 224;
    __hip_bfloat16 h, l;
    bsplit(v0 * rs, h, l); hp[lane] = h;       lp[lane] = l;
    bsplit(v1 * rs, h, l); hp[lane + 64] = h;  lp[lane + 64] = l;
    bsplit(v2 * rs, h, l); hp[lane + 128] = h; lp[lane + 128] = l;
    if (j3 < 224) {
        float pv = (j3 < 197) ? v3 * rs : 0.f;
        bsplit(pv, h, l); hp[j3] = h; lp[j3] = l;
    }
}

// ---------------------------------------------------------------------------
// Split-bf16 emulated-fp32 MFMA GEMM: C = (Ah+Al)[M,K] @ (Bh+Bl)[N,K]^T
// using Ah.Bh + Ah.Bl + Al.Bh.  64x64 tile, 4 waves, 2x2 16x16x32 frags.
// ---------------------------------------------------------------------------
enum { M_QKV = 0, M_SCORES = 1, M_AV = 2, M_BIAS_RES = 3, M_FF1 = 4, M_HEAD = 5, M_EMBED = 6 };

template <int MODE>
__global__ __launch_bounds__(256) void gemm_bt(
    const short* __restrict__ Ah, const short* __restrict__ Al,
    const short* __restrict__ Bh, const short* __restrict__ Bl,
    const float* __restrict__ bias, const float* __restrict__ resid,
    const float* __restrict__ aux, void* __restrict__ Cv, void* __restrict__ Cv2,
    int M, int N, int K, int lda, int ldb, int ldc)
{
    __shared__ __align__(16) short lAh[2048], lAl[2048], lBh[2048], lBl[2048];
    int z = blockIdx.z;
    if (MODE == M_SCORES) { long o = (long)z * 12608; Ah += o; Al += o; Bh += o; Bl += o; }
    if (MODE == M_AV)     { long oa = (long)z * 88256, ob = (long)z * 14336;
                            Ah += oa; Al += oa; Bh += ob; Bl += ob; }
    int tid = threadIdx.x;
    int lane = tid & 63;
    int quad = lane >> 4, mr = lane & 15;
    int wave = tid >> 6;
    int wm = (wave >> 1) << 5, wn = (wave & 1) << 5;
    int tm = blockIdx.y, tn = blockIdx.x;
    int srow = tid >> 2, skq = tid & 3;
    int sdst = (((srow >> 4) << 2) + skq) * 128 + (srow & 15) * 8;
    int arow = (tm << 6) + srow, brow = (tn << 6) + srow;
    bool aval = arow < M, bval = brow < N;
    const short* aph = Ah + (long)arow * lda + (skq << 3);
    const short* apl = Al + (long)arow * lda + (skq << 3);
    const short* bph = Bh + (long)brow * ldb + (skq << 3);
    const short* bpl = Bl + (long)brow * ldb + (skq << 3);
    f4v zf = {0.f, 0.f, 0.f, 0.f};
    f4v acc00 = zf, acc01 = zf, acc10 = zf, acc11 = zf;
    int fa0 = ((wm >> 4) * 64 + lane) * 8;
    int fa1 = fa0 + 512;
    int fb0 = ((wn >> 4) * 64 + lane) * 8;
    int fb1 = fb0 + 512;
    s8v zs = {0, 0, 0, 0, 0, 0, 0, 0};
    for (int k0 = 0; k0 < K; k0 += 32) {
        s8v vah = aval ? *(const s8v*)aph : zs;
        s8v val_ = aval ? *(const s8v*)apl : zs;
        s8v vbh = bval ? *(const s8v*)bph : zs;
        s8v vbl = bval ? *(const s8v*)bpl : zs;
        aph += 32; apl += 32; bph += 32; bpl += 32;
        __syncthreads();
        *(s8v*)(lAh + sdst) = vah;
        *(s8v*)(lAl + sdst) = val_;
        *(s8v*)(lBh + sdst) = vbh;
        *(s8v*)(lBl + sdst) = vbl;
        __syncthreads();
        s8v a0h = *(const s8v*)(lAh + fa0);
        s8v a1h = *(const s8v*)(lAh + fa1);
        s8v a0l = *(const s8v*)(lAl + fa0);
        s8v a1l = *(const s8v*)(lAl + fa1);
        s8v b0h = *(const s8v*)(lBh + fb0);
        s8v b1h = *(const s8v*)(lBh + fb1);
        s8v b0l = *(const s8v*)(lBl + fb0);
        s8v b1l = *(const s8v*)(lBl + fb1);
        acc00 = __builtin_amdgcn_mfma_f32_16x16x32_bf16(a0h, b0h, acc00, 0, 0, 0);
        acc01 = __builtin_amdgcn_mfma_f32_16x16x32_bf16(a0h, b1h, acc01, 0, 0, 0);
        acc10 = __builtin_amdgcn_mfma_f32_16x16x32_bf16(a1h, b0h, acc10, 0, 0, 0);
        acc11 = __builtin_amdgcn_mfma_f32_16x16x32_bf16(a1h, b1h, acc11, 0, 0, 0);
        acc00 = __builtin_amdgcn_mfma_f32_16x16x32_bf16(a0h, b0l, acc00, 0, 0, 0);
        acc01 = __builtin_amdgcn_mfma_f32_16x16x32_bf16(a0h, b1l, acc01, 0, 0, 0);
        acc10 = __builtin_amdgcn_mfma_f32_16x16x32_bf16(a1h, b0l, acc10, 0, 0, 0);
        acc11 = __builtin_amdgcn_mfma_f32_16x16x32_bf16(a1h, b1l, acc11, 0, 0, 0);
        acc00 = __builtin_amdgcn_mfma_f32_16x16x32_bf16(a0l, b0h, acc00, 0, 0, 0);
        acc01 = __builtin_amdgcn_mfma_f32_16x16x32_bf16(a0l, b1h, acc01, 0, 0, 0);
        acc10 = __builtin_amdgcn_mfma_f32_16x16x32_bf16(a1l, b0h, acc10, 0, 0, 0);
        acc11 = __builtin_amdgcn_mfma_f32_16x16x32_bf16(a1l, b1h, acc11, 0, 0, 0);
    }
    f4v accs[2][2] = {{acc00, acc01}, {acc10, acc11}};
    #pragma unroll
    for (int mi = 0; mi < 2; mi++)
    #pragma unroll
    for (int ni = 0; ni < 2; ni++) {
        f4v ac = accs[mi][ni];
        #pragma unroll
        for (int r = 0; r < 4; r++) {
            int gm = (tm << 6) + wm + (mi << 4) + (quad << 2) + r;
            int gn = (tn << 6) + wn + (ni << 4) + mr;
            if (gm >= M || gn >= N) continue;
            float v = ac[r];
            if (MODE == M_QKV) {
                ((float*)Cv)[(long)gm * ldc + gn] = v + bias[gn];
            } else if (MODE == M_SCORES) {
                ((float*)Cv)[(long)z * 44128 + (long)gm * 224 + gn] = v * 8.f;
            } else if (MODE == M_AV) {
                int bb2 = z / 12, h = z - bb2 * 12;
                long di = (long)(bb2 * 197 + gm) * 768 + h * 64 + gn;
                __hip_bfloat16 hh, ll;
                bsplit(v, hh, ll);
                ((__hip_bfloat16*)Cv)[di] = hh;
                ((__hip_bfloat16*)Cv2)[di] = ll;
            } else if (MODE == M_BIAS_RES) {
                ((float*)Cv)[(long)gm * ldc + gn] = v + bias[gn] + resid[(long)gm * ldc + gn];
            } else if (MODE == M_FF1) {
                v = fmaxf(v + bias[gn], 0.f);
                __hip_bfloat16 hh, ll;
                bsplit(v, hh, ll);
                ((__hip_bfloat16*)Cv)[(long)gm * ldc + gn] = hh;
                ((__hip_bfloat16*)Cv2)[(long)gm * ldc + gn] = ll;
            } else if (MODE == M_HEAD) {
                ((float*)Cv)[(long)gm * ldc + gn] = v + bias[gn];
            } else if (MODE == M_EMBED) {
                v = fmaxf(v * bias[gn] + resid[gn], 0.f);  // BN scale/shift + ReLU
                int bb2 = gm / 196, p = gm - bb2 * 196;
                v += aux[(p + 1) * 768 + gn];              // pos_enc
                ((float*)Cv)[(long)(bb2 * 197 + p + 1) * 768 + gn] = v;
            }
        }
    }
}

// ---------------------------------------------------------------------------
extern "C" void kernel_launch(void* const* d_in, const int* in_sizes, int n_in,
                              void* d_out, int out_size, void* d_ws, size_t ws_size,
                              hipStream_t stream)
{
    (void)in_sizes; (void)n_in; (void)out_size; (void)ws_size;
    const float* x_in = (const float*)d_in[0];
    const float *conv_w[5], *bng[5], *bnb[5], *bnm[5], *bnv[5];
    for (int i = 0; i < 5; i++) {
        conv_w[i] = (const float*)d_in[1 + i * 5];
        bng[i]    = (const float*)d_in[2 + i * 5];
        bnb[i]    = (const float*)d_in[3 + i * 5];
        bnm[i]    = (const float*)d_in[4 + i * 5];
        bnv[i]    = (const float*)d_in[5 + i * 5];
    }
    const float* cls_token = (const float*)d_in[26];
    const float* pos_enc   = (const float*)d_in[27];
    const float* ln1_a = (const float*)d_in[28];
    const float* ln1_b = (const float*)d_in[29];
    const float* qkv_w = (const float*)d_in[30];
    const float* qkv_b = (const float*)d_in[31];
    const float* proj_w = (const float*)d_in[32];
    const float* proj_b = (const float*)d_in[33];
    const float* ln2_a = (const float*)d_in[34];
    const float* ln2_b = (const float*)d_in[35];
    const float* ff1_w = (const float*)d_in[36];
    const float* ff1_b = (const float*)d_in[37];
    const float* ff2_w = (const float*)d_in[38];
    const float* ff2_b = (const float*)d_in[39];
    const float* norm_a = (const float*)d_in[40];
    const float* norm_b = (const float*)d_in[41];
    const float* fc_w  = (const float*)d_in[42];
    const float* fc_b  = (const float*)d_in[43];

    char* ws = (char*)d_ws;
    size_t off = 0;
    auto alloc = [&](size_t bytes) {
        off = (off + 255) & ~(size_t)255;
        char* p = ws + off;
        off += bytes;
        return p;
    };
    char* arena = (char*)alloc(154140672);
    float* xbuf = (float*)alloc(19365888);                       // [32,197,768] fp32
    __hip_bfloat16* yh  = (__hip_bfloat16*)alloc(9682944);
    __hip_bfloat16* yl  = (__hip_bfloat16*)alloc(9682944);
    __hip_bfloat16* aoh = (__hip_bfloat16*)alloc(9682944);
    __hip_bfloat16* aol = (__hip_bfloat16*)alloc(9682944);
    __hip_bfloat16* A4h = (__hip_bfloat16*)alloc(6422528);
    __hip_bfloat16* A4l = (__hip_bfloat16*)alloc(6422528);
    __hip_bfloat16* wqkvh = (__hip_bfloat16*)alloc(3538944);
    __hip_bfloat16* wqkvl = (__hip_bfloat16*)alloc(3538944);
    __hip_bfloat16* wprojh = (__hip_bfloat16*)alloc(1179648);
    __hip_bfloat16* wprojl = (__hip_bfloat16*)alloc(1179648);
    __hip_bfloat16* wff1h = (__hip_bfloat16*)alloc(4718592);
    __hip_bfloat16* wff1l = (__hip_bfloat16*)alloc(4718592);
    __hip_bfloat16* wff2h = (__hip_bfloat16*)alloc(4718592);
    __hip_bfloat16* wff2l = (__hip_bfloat16*)alloc(4718592);
    __hip_bfloat16* wfch = (__hip_bfloat16*)alloc(1536000);
    __hip_bfloat16* wfcl = (__hip_bfloat16*)alloc(1536000);
    __hip_bfloat16* wc4h = (__hip_bfloat16*)alloc(786432);
    __hip_bfloat16* wc4l = (__hip_bfloat16*)alloc(786432);
    float* bn4s = (float*)alloc(3072);
    float* bn4b = (float*)alloc(3072);
    __hip_bfloat16* hlnh = (__hip_bfloat16*)alloc(49152);
    __hip_bfloat16* hlnl = (__hip_bfloat16*)alloc(49152);

    // arena lifetime map
    float* s0 = (float*)arena;                       // conv0 out (102.76 MB)
    float* s1 = (float*)(arena + 102760448);         // conv1 out (51.38 MB)
    float* s2 = (float*)arena;                       // conv2 out (25.7 MB)
    float* s3 = (float*)(arena + 102760448);         // conv3 out (12.8 MB)
    float* qkvf = (float*)arena;                     // qkv fp32 (58.1 MB)
    float* Sbuf = (float*)arena;                     // scores fp32 (67.78 MB), att packed in-place
    __hip_bfloat16* qh = (__hip_bfloat16*)(arena + 67780608);
    __hip_bfloat16* ql = (__hip_bfloat16*)(arena + 77463552);
    __hip_bfloat16* kh = (__hip_bfloat16*)(arena + 87146496);
    __hip_bfloat16* kl = (__hip_bfloat16*)(arena + 96829440);
    __hip_bfloat16* vTh = (__hip_bfloat16*)(arena + 106512384);
    __hip_bfloat16* vTl = (__hip_bfloat16*)(arena + 117522432);
    __hip_bfloat16* hffh = (__hip_bfloat16*)arena;                 // 38.73 MB
    __hip_bfloat16* hffl = (__hip_bfloat16*)(arena + 38731776);    // 38.73 MB

    // ---- conv stem (fp32 direct) ----
    conv3x3_s2<<<dim3(49, 64, 32), 256, 27 * 4, stream>>>(
        x_in, conv_w[0], bng[0], bnb[0], bnm[0], bnv[0], s0, 3, 64, 224, 224, 112, 112);
    conv3x3_s2<<<dim3(13, 128, 32), 256, 576 * 4, stream>>>(
        s0, conv_w[1], bng[1], bnb[1], bnm[1], bnv[1], s1, 64, 128, 112, 112, 56, 56);
    conv3x3_s2<<<dim3(4, 256, 32), 256, 1152 * 4, stream>>>(
        s1, conv_w[2], bng[2], bnb[2], bnm[2], bnv[2], s2, 128, 256, 56, 56, 28, 28);
    conv3x3_s2<<<dim3(1, 512, 32), 256, 2304 * 4, stream>>>(
        s2, conv_w[3], bng[3], bnb[3], bnm[3], bnv[3], s3, 256, 512, 28, 28, 14, 14);

    // ---- conv4 (1x1) as split GEMM + embed ----
    bn_prep<<<dim3(3), 256, 0, stream>>>(bng[4], bnb[4], bnm[4], bnv[4], bn4s, bn4b, 768);
    f32_split_k<<<dim3(1536), 256, 0, stream>>>(conv_w[4], wc4h, wc4l, 393216);
    transpose_split<<<dim3(7, 16, 32), 256, 0, stream>>>(s3, A4h, A4l, 512, 196);
    cls_embed<<<dim3(96), 256, 0, stream>>>(cls_token, pos_enc, xbuf);
    gemm_bt<M_EMBED><<<dim3(12, 98, 1), 256, 0, stream>>>(
        (const short*)A4h, (const short*)A4l, (const short*)wc4h, (const short*)wc4l,
        bn4s, bn4b, pos_enc, xbuf, nullptr, 6272, 768, 512, 512, 512, 768);

    // ---- 12 transformer layers ----
    for (int l = 0; l < 12; l++) {
        transpose_split<<<dim3(72, 24, 1), 256, 0, stream>>>(
            qkv_w + (long)l * 768 * 2304, wqkvh, wqkvl, 768, 2304);
        transpose_split<<<dim3(24, 24, 1), 256, 0, stream>>>(
            proj_w + (long)l * 768 * 768, wprojh, wprojl, 768, 768);
        transpose_split<<<dim3(96, 24, 1), 256, 0, stream>>>(
            ff1_w + (long)l * 768 * 3072, wff1h, wff1l, 768, 3072);
        transpose_split<<<dim3(24, 96, 1), 256, 0, stream>>>(
            ff2_w + (long)l * 3072 * 768, wff2h, wff2l, 3072, 768);

        ln_fwd<<<dim3(6304), 256, 0, stream>>>(
            xbuf, 768L, ln1_a + l * 768, ln1_b + l * 768, yh, yl, 6304);
        gemm_bt<M_QKV><<<dim3(36, 99, 1), 256, 0, stream>>>(
            (const short*)yh, (const short*)yl, (const short*)wqkvh, (const short*)wqkvl,
            qkv_b + l * 2304, nullptr, nullptr, qkvf, nullptr,
            6304, 2304, 768, 768, 768, 2304);
        repack_qk_f<<<dim3(37824), 256, 0, stream>>>(qkvf, qh, ql, kh, kl);
        repack_v_f<<<dim3(4, 384), 256, 0, stream>>>(qkvf, vTh, vTl);
        gemm_bt<M_SCORES><<<dim3(4, 4, 384), 256, 0, stream>>>(
            (const short*)qh, (const short*)ql, (const short*)kh, (const short*)kl,
            nullptr, nullptr, nullptr, Sbuf, nullptr, 197, 197, 64, 64, 64, 224);
        softmax_k<<<dim3(18912), 256, 0, stream>>>(Sbuf, 75648);
        gemm_bt<M_AV><<<dim3(1, 4, 384), 256, 0, stream>>>(
            (const short*)Sbuf, (const short*)Sbuf + 224, (const short*)vTh, (const short*)vTl,
            nullptr, nullptr, nullptr, aoh, aol, 197, 64, 224, 448, 224, 768);
        gemm_bt<M_BIAS_RES><<<dim3(12, 99, 1), 256, 0, stream>>>(
            (const short*)aoh, (const short*)aol, (const short*)wprojh, (const short*)wprojl,
            proj_b + l * 768, xbuf, nullptr, xbuf, nullptr,
            6304, 768, 768, 768, 768, 768);
        ln_fwd<<<dim3(6304), 256, 0, stream>>>(
            xbuf, 768L, ln2_a + l * 768, ln2_b + l * 768, yh, yl, 6304);
        gemm_bt<M_FF1><<<dim3(48, 99, 1), 256, 0, stream>>>(
            (const short*)yh, (const short*)yl, (const short*)wff1h, (const short*)wff1l,
            ff1_b + l * 3072, nullptr, nullptr, hffh, hffl,
            6304, 3072, 768, 768, 768, 3072);
        gemm_bt<M_BIAS_RES><<<dim3(12, 99, 1), 256, 0, stream>>>(
            (const short*)hffh, (const short*)hffl, (const short*)wff2h, (const short*)wff2l,
            ff2_b + l * 768, xbuf, nullptr, xbuf, nullptr,
            6304, 768, 3072, 3072, 3072, 768);
    }

    // ---- head ----
    transpose_split<<<dim3(32, 24, 1), 256, 0, stream>>>(fc_w, wfch, wfcl, 768, 1000);
    ln_fwd<<<dim3(32), 256, 0, stream>>>(xbuf, 197L * 768L, norm_a, norm_b, hlnh, hlnl, 32);
    gemm_bt<M_HEAD><<<dim3(16, 1, 1), 256, 0, stream>>>(
        (const short*)hlnh, (const short*)hlnl, (const short*)wfch, (const short*)wfcl,
        fc_b, nullptr, nullptr, d_out, nullptr, 32, 1000, 768, 768, 768, 1000);
}

// Round 4
// 8629.535 us; speedup vs baseline: 2.6089x; 2.6089x over previous
//
#include <hip/hip_runtime.h>
#include <hip/hip_bf16.h>

typedef short s8v __attribute__((ext_vector_type(8)));
typedef float f4v __attribute__((ext_vector_type(4)));

__device__ inline void bsplit(float v, __hip_bfloat16& h, __hip_bfloat16& l) {
    h = __float2bfloat16(v);
    l = __float2bfloat16(v - __bfloat162float(h));
}

// ---------------------------------------------------------------------------
// conv0: 3->64, 3x3 s2 p1, 224->112. Direct, input tile in LDS, weights via
// scalar cache (block-uniform). Emits channels-last bf16 hi/lo planes.
// ---------------------------------------------------------------------------
__global__ __launch_bounds__(256) void conv0_k(
    const float* __restrict__ in, const float* __restrict__ w,
    const float* __restrict__ bnS, const float* __restrict__ bnB,
    short* __restrict__ Yh, short* __restrict__ Yl)
{
    __shared__ float tile[3267];  // 3 x 33 x 33
    int b = blockIdx.z;
    int oy0 = blockIdx.y << 4, ox0 = blockIdx.x << 4;
    int iy0 = (oy0 << 1) - 1, ix0 = (ox0 << 1) - 1;
    const float* ib = in + (long)b * 3 * 224 * 224;
    for (int idx = threadIdx.x; idx < 3267; idx += 256) {
        int ci = idx / 1089, r = idx - ci * 1089;
        int ry = r / 33, rx = r - ry * 33;
        int iy = iy0 + ry, ix = ix0 + rx;
        float v = 0.f;
        if ((unsigned)iy < 224u && (unsigned)ix < 224u) v = ib[(ci * 224 + iy) * 224 + ix];
        tile[idx] = v;
    }
    __syncthreads();
    int tx = threadIdx.x & 15, ty = threadIdx.x >> 4;
    float xin[27];
    #pragma unroll
    for (int ci = 0; ci < 3; ci++)
        #pragma unroll
        for (int ky = 0; ky < 3; ky++)
            #pragma unroll
            for (int kx = 0; kx < 3; kx++)
                xin[(ci * 3 + ky) * 3 + kx] =
                    tile[ci * 1089 + ((ty << 1) + ky) * 33 + (tx << 1) + kx];
    int oy = oy0 + ty, ox = ox0 + tx;
    long obase = (((long)b * 112 + oy) * 112 + ox) << 6;
    #pragma unroll 1
    for (int cg = 0; cg < 8; cg++) {
        s8v hv, lv;
        #pragma unroll
        for (int j = 0; j < 8; j++) {
            int co = (cg << 3) + j;
            const float* wp = w + co * 27;
            float acc = 0.f;
            #pragma unroll
            for (int i = 0; i < 27; i++) acc = fmaf(wp[i], xin[i], acc);
            float y = fmaxf(acc * bnS[co] + bnB[co], 0.f);
            __hip_bfloat16 h, l;
            bsplit(y, h, l);
            hv[j] = __bfloat16_as_short(h);
            lv[j] = __bfloat16_as_short(l);
        }
        *(s8v*)(Yh + obase + (cg << 3)) = hv;
        *(s8v*)(Yl + obase + (cg << 3)) = lv;
    }
}

// ---------------------------------------------------------------------------
// Conv weight repack: OIHW fp32 -> [Cout][tap*Cin+ci] bf16 hi/lo
// ---------------------------------------------------------------------------
__global__ __launch_bounds__(256) void repack_cw(
    const float* __restrict__ w, __hip_bfloat16* __restrict__ dh,
    __hip_bfloat16* __restrict__ dl, int Cin, int cinShift, int K, long total)
{
    long idx = (long)blockIdx.x * 256 + threadIdx.x;
    if (idx >= total) return;
    int co = (int)(idx / K), k = (int)(idx - (long)co * K);
    int tap = k >> cinShift, ci = k & (Cin - 1);
    float v = w[(long)(co * Cin + ci) * 9 + tap];
    __hip_bfloat16 h, l;
    bsplit(v, h, l);
    dh[idx] = h;
    dl[idx] = l;
}

// ---------------------------------------------------------------------------
// Implicit-GEMM conv (3x3 s2 p1), channels-last bf16 hi/lo in/out, split-bf16
// fp32-emulated MFMA.  64x64 tile, 4 waves, 2x2 frags, 12 MFMA per K32.
// ---------------------------------------------------------------------------
__global__ __launch_bounds__(256) void conv_gemm(
    const short* __restrict__ Xh, const short* __restrict__ Xl,
    const short* __restrict__ Wh, const short* __restrict__ Wl,
    const float* __restrict__ bnS, const float* __restrict__ bnB,
    short* __restrict__ Yh, short* __restrict__ Yl,
    int Hi, int Wi, int Ho, int Wo, int cinShift, int Cout, int K)
{
    __shared__ __align__(16) short lAh[2048], lAl[2048], lBh[2048], lBl[2048];
    int tid = threadIdx.x;
    int lane = tid & 63;
    int quad = lane >> 4, mr = lane & 15;
    int wave = tid >> 6;
    int wm = (wave >> 1) << 5, wn = (wave & 1) << 5;
    int tm = blockIdx.y, tn = blockIdx.x;
    int srow = tid >> 2, skq = tid & 3;
    int sdst = (((srow >> 4) << 2) + skq) * 128 + (srow & 15) * 8;
    int m = (tm << 6) + srow;
    int HWo = Ho * Wo;
    int b = m / HWo, sp = m - b * HWo;
    int oy = sp / Wo, ox = sp - oy * Wo;
    int iy0 = (oy << 1) - 1, ix0 = (ox << 1) - 1;
    long ibase = ((long)b * Hi * Wi) << cinShift;
    int cmask = (1 << cinShift) - 1;
    int brow = (tn << 6) + srow;
    const short* bph = Wh + (long)brow * K + (skq << 3);
    const short* bpl = Wl + (long)brow * K + (skq << 3);
    f4v zf = {0.f, 0.f, 0.f, 0.f};
    f4v acc00 = zf, acc01 = zf, acc10 = zf, acc11 = zf;
    int fa0 = ((wm >> 4) * 64 + lane) * 8;
    int fa1 = fa0 + 512;
    int fb0 = ((wn >> 4) * 64 + lane) * 8;
    int fb1 = fb0 + 512;
    s8v zs = {0, 0, 0, 0, 0, 0, 0, 0};
    for (int k0 = 0; k0 < K; k0 += 32) {
        int k = k0 + (skq << 3);
        int tap = k >> cinShift, ci = k & cmask;
        int ky = (tap >= 6) ? 2 : ((tap >= 3) ? 1 : 0);
        int kx = tap - ky * 3;
        int iy = iy0 + ky, ix = ix0 + kx;
        bool v = ((unsigned)iy < (unsigned)Hi) & ((unsigned)ix < (unsigned)Wi);
        long addr = ibase + (((long)iy * Wi + ix) << cinShift) + ci;
        s8v vah = v ? *(const s8v*)(Xh + addr) : zs;
        s8v val_ = v ? *(const s8v*)(Xl + addr) : zs;
        s8v vbh = *(const s8v*)bph;
        s8v vbl = *(const s8v*)bpl;
        bph += 32; bpl += 32;
        __syncthreads();
        *(s8v*)(lAh + sdst) = vah;
        *(s8v*)(lAl + sdst) = val_;
        *(s8v*)(lBh + sdst) = vbh;
        *(s8v*)(lBl + sdst) = vbl;
        __syncthreads();
        s8v a0h = *(const s8v*)(lAh + fa0);
        s8v a1h = *(const s8v*)(lAh + fa1);
        s8v a0l = *(const s8v*)(lAl + fa0);
        s8v a1l = *(const s8v*)(lAl + fa1);
        s8v b0h = *(const s8v*)(lBh + fb0);
        s8v b1h = *(const s8v*)(lBh + fb1);
        s8v b0l = *(const s8v*)(lBl + fb0);
        s8v b1l = *(const s8v*)(lBl + fb1);
        acc00 = __builtin_amdgcn_mfma_f32_16x16x32_bf16(a0h, b0h, acc00, 0, 0, 0);
        acc01 = __builtin_amdgcn_mfma_f32_16x16x32_bf16(a0h, b1h, acc01, 0, 0, 0);
        acc10 = __builtin_amdgcn_mfma_f32_16x16x32_bf16(a1h, b0h, acc10, 0, 0, 0);
        acc11 = __builtin_amdgcn_mfma_f32_16x16x32_bf16(a1h, b1h, acc11, 0, 0, 0);
        acc00 = __builtin_amdgcn_mfma_f32_16x16x32_bf16(a0h, b0l, acc00, 0, 0, 0);
        acc01 = __builtin_amdgcn_mfma_f32_16x16x32_bf16(a0h, b1l, acc01, 0, 0, 0);
        acc10 = __builtin_amdgcn_mfma_f32_16x16x32_bf16(a1h, b0l, acc10, 0, 0, 0);
        acc11 = __builtin_amdgcn_mfma_f32_16x16x32_bf16(a1h, b1l, acc11, 0, 0, 0);
        acc00 = __builtin_amdgcn_mfma_f32_16x16x32_bf16(a0l, b0h, acc00, 0, 0, 0);
        acc01 = __builtin_amdgcn_mfma_f32_16x16x32_bf16(a0l, b1h, acc01, 0, 0, 0);
        acc10 = __builtin_amdgcn_mfma_f32_16x16x32_bf16(a1l, b0h, acc10, 0, 0, 0);
        acc11 = __builtin_amdgcn_mfma_f32_16x16x32_bf16(a1l, b1h, acc11, 0, 0, 0);
    }
    f4v accs[2][2] = {{acc00, acc01}, {acc10, acc11}};
    #pragma unroll
    for (int mi = 0; mi < 2; mi++)
    #pragma unroll
    for (int ni = 0; ni < 2; ni++) {
        f4v ac = accs[mi][ni];
        #pragma unroll
        for (int r = 0; r < 4; r++) {
            int gm = (tm << 6) + wm + (mi << 4) + (quad << 2) + r;
            int gn = (tn << 6) + wn + (ni << 4) + mr;
            float y = fmaxf(ac[r] * bnS[gn] + bnB[gn], 0.f);
            __hip_bfloat16 h, l;
            bsplit(y, h, l);
            Yh[(long)gm * Cout + gn] = __bfloat16_as_short(h);
            Yl[(long)gm * Cout + gn] = __bfloat16_as_short(l);
        }
    }
}

// ---------------------------------------------------------------------------
// Tiled transpose fp32 [z][K][N] -> bf16 hi/lo [z][N][K]
// ---------------------------------------------------------------------------
__global__ __launch_bounds__(256) void transpose_split(
    const float* __restrict__ src, __hip_bfloat16* __restrict__ dh,
    __hip_bfloat16* __restrict__ dl, int K, int N)
{
    __shared__ float tile[32][33];
    int z = blockIdx.z;
    long so = (long)z * K * N;
    int n0 = blockIdx.x * 32, k0 = blockIdx.y * 32;
    int tx = threadIdx.x & 31, ty = threadIdx.x >> 5;
    #pragma unroll
    for (int r = 0; r < 32; r += 8) {
        int k = k0 + ty + r, n = n0 + tx;
        tile[ty + r][tx] = (k < K && n < N) ? src[so + (long)k * N + n] : 0.f;
    }
    __syncthreads();
    #pragma unroll
    for (int r = 0; r < 32; r += 8) {
        int n = n0 + ty + r, k = k0 + tx;
        if (n < N && k < K) {
            __hip_bfloat16 h, l;
            bsplit(tile[tx][ty + r], h, l);
            dh[so + (long)n * K + k] = h;
            dl[so + (long)n * K + k] = l;
        }
    }
}

__global__ __launch_bounds__(256) void f32_split_k(
    const float* __restrict__ s, __hip_bfloat16* __restrict__ dh,
    __hip_bfloat16* __restrict__ dl, long n)
{
    long i = (long)blockIdx.x * 256 + threadIdx.x;
    if (i < n) { __hip_bfloat16 h, l; bsplit(s[i], h, l); dh[i] = h; dl[i] = l; }
}

__global__ __launch_bounds__(256) void bn_prep(
    const float* __restrict__ g, const float* __restrict__ b,
    const float* __restrict__ m, const float* __restrict__ v,
    float* __restrict__ sc, float* __restrict__ bs, int n)
{
    int i = blockIdx.x * 256 + threadIdx.x;
    if (i < n) {
        float s = g[i] * rsqrtf(v[i] + 1e-5f);
        sc[i] = s;
        bs[i] = b[i] - m[i] * s;
    }
}

__global__ __launch_bounds__(256) void cls_embed(
    const float* __restrict__ cls, const float* __restrict__ pos, float* __restrict__ x)
{
    int i = blockIdx.x * 256 + threadIdx.x;  // 32*768
    if (i >= 32 * 768) return;
    int b = i / 768, c = i - b * 768;
    x[(long)b * 197 * 768 + c] = cls[c] + pos[c];
}

// ---------------------------------------------------------------------------
// LayerNorm (unbiased var, eps on std) fp32 -> bf16 hi/lo
// ---------------------------------------------------------------------------
__global__ __launch_bounds__(256) void ln_fwd(
    const float* __restrict__ in, long rowStride,
    const float* __restrict__ a, const float* __restrict__ bb,
    __hip_bfloat16* __restrict__ oh, __hip_bfloat16* __restrict__ ol, int nrows)
{
    int row = blockIdx.x;
    if (row >= nrows) return;
    const float* p = in + (long)row * rowStride;
    int t = threadIdx.x;
    float v0 = p[t], v1 = p[t + 256], v2 = p[t + 512];
    float s = v0 + v1 + v2;
    float sq = v0 * v0 + v1 * v1 + v2 * v2;
    #pragma unroll
    for (int o = 32; o > 0; o >>= 1) { s += __shfl_xor(s, o); sq += __shfl_xor(sq, o); }
    __shared__ float red[8];
    int wv = t >> 6;
    if ((t & 63) == 0) { red[wv] = s; red[wv + 4] = sq; }
    __syncthreads();
    s = red[0] + red[1] + red[2] + red[3];
    sq = red[4] + red[5] + red[6] + red[7];
    float mu = s * (1.f / 768.f);
    float var = fmaxf((sq - 768.f * mu * mu) * (1.f / 767.f), 0.f);
    float inv = 1.f / (sqrtf(var) + 1e-4f);
    long ro = (long)row * 768;
    #pragma unroll
    for (int j = 0; j < 3; j++) {
        int c = t + j * 256;
        float vv = (j == 0) ? v0 : (j == 1) ? v1 : v2;
        float y = a[c] * ((vv - mu) * inv) + bb[c];
        __hip_bfloat16 h, l;
        bsplit(y, h, l);
        oh[ro + c] = h;
        ol[ro + c] = l;
    }
}

// ---------------------------------------------------------------------------
// Repack qkv fp32 [6304][2304] -> q,k hi/lo [bh][197][64]
// ---------------------------------------------------------------------------
__global__ __launch_bounds__(256) void repack_qk_f(
    const float* __restrict__ qkv,
    __hip_bfloat16* __restrict__ qh, __hip_bfloat16* __restrict__ ql,
    __hip_bfloat16* __restrict__ kh, __hip_bfloat16* __restrict__ kl)
{
    long idx = (long)blockIdx.x * 256 + threadIdx.x;
    const long half = 6304L * 768;
    if (idx >= 2 * half) return;
    int which = idx >= half;
    long r = idx - (long)which * half;
    int tok = (int)(r / 768), c = (int)(r - (long)tok * 768);
    int b = tok / 197, i = tok - b * 197;
    int h = c >> 6, d = c & 63;
    float val = qkv[(long)tok * 2304 + which * 768 + c];
    __hip_bfloat16 vh, vl;
    bsplit(val, vh, vl);
    long di = ((long)(b * 12 + h) * 197 + i) * 64 + d;
    if (which) { kh[di] = vh; kl[di] = vl; } else { qh[di] = vh; ql[di] = vl; }
}

// v -> vT hi/lo [bh][64][224] (pads zeroed)
__global__ __launch_bounds__(256) void repack_v_f(
    const float* __restrict__ qkv, __hip_bfloat16* __restrict__ vh,
    __hip_bfloat16* __restrict__ vl)
{
    int bh = blockIdx.y, j0 = blockIdx.x * 64;
    int b = bh / 12, h = bh - b * 12;
    __shared__ float tl[64][65];
    int tx = threadIdx.x & 63, ty4 = threadIdx.x >> 6;
    #pragma unroll
    for (int r = 0; r < 64; r += 4) {
        int j = j0 + ty4 + r;
        tl[ty4 + r][tx] = (j < 197)
            ? qkv[(long)(b * 197 + j) * 2304 + 1536 + h * 64 + tx] : 0.f;
    }
    __syncthreads();
    #pragma unroll
    for (int r = 0; r < 64; r += 4) {
        int d = ty4 + r, jl = tx, j = j0 + jl;
        if (j < 224) {
            __hip_bfloat16 hh, ll;
            bsplit(tl[jl][d], hh, ll);
            long di = ((long)bh * 64 + d) * 224 + j;
            vh[di] = hh; vl[di] = ll;
        }
    }
}

// ---------------------------------------------------------------------------
// Softmax on S fp32 [row][224] (valid 197); writes att hi/lo bf16 packed
// IN-PLACE into the same row (448 bf16 slots: [0,224)=hi, [224,448)=lo).
// ---------------------------------------------------------------------------
__global__ __launch_bounds__(256) void softmax_k(
    float* __restrict__ S, int nrows)
{
    int row = blockIdx.x * 4 + (threadIdx.x >> 6);
    if (row >= nrows) return;
    int lane = threadIdx.x & 63;
    float* sp = S + (long)row * 224;
    float v0 = sp[lane];
    float v1 = sp[lane + 64];
    float v2 = sp[lane + 128];
    int j3 = lane + 192;
    float v3 = (j3 < 197) ? sp[j3] : -1e30f;
    float mx = fmaxf(fmaxf(v0, v1), fmaxf(v2, v3));
    #pragma unroll
    for (int o = 32; o > 0; o >>= 1) mx = fmaxf(mx, __shfl_xor(mx, o));
    v0 = __expf(v0 - mx); v1 = __expf(v1 - mx); v2 = __expf(v2 - mx);
    v3 = (j3 < 197) ? __expf(v3 - mx) : 0.f;
    float s = v0 + v1 + v2 + v3;
    #pragma unroll
    for (int o = 32; o > 0; o >>= 1) s += __shfl_xor(s, o);
    float rs = 1.f / s;
    __hip_bfloat16* hp = (__hip_bfloat16*)sp;        // 448 slots
    __hip_bfloat16* lp = hp + 224;
    __hip_bfloat16 h, l;
    bsplit(v0 * rs, h, l); hp[lane] = h;       lp[lane] = l;
    bsplit(v1 * rs, h, l); hp[lane + 64] = h;  lp[lane + 64] = l;
    bsplit(v2 * rs, h, l); hp[lane + 128] = h; lp[lane + 128] = l;
    if (j3 < 224) {
        float pv = (j3 < 197) ? v3 * rs : 0.f;
        bsplit(pv, h, l); hp[j3] = h; lp[j3] = l;
    }
}

// ---------------------------------------------------------------------------
// Split-bf16 emulated-fp32 MFMA GEMM: C = (Ah+Al)[M,K] @ (Bh+Bl)[N,K]^T
// using Ah.Bh + Ah.Bl + Al.Bh.  64x64 tile, 4 waves, 2x2 16x16x32 frags.
// ---------------------------------------------------------------------------
enum { M_QKV = 0, M_SCORES = 1, M_AV = 2, M_BIAS_RES = 3, M_FF1 = 4, M_HEAD = 5, M_EMBED = 6 };

template <int MODE>
__global__ __launch_bounds__(256) void gemm_bt(
    const short* __restrict__ Ah, const short* __restrict__ Al,
    const short* __restrict__ Bh, const short* __restrict__ Bl,
    const float* __restrict__ bias, const float* __restrict__ resid,
    const float* __restrict__ aux, void* __restrict__ Cv, void* __restrict__ Cv2,
    int M, int N, int K, int lda, int ldb, int ldc)
{
    __shared__ __align__(16) short lAh[2048], lAl[2048], lBh[2048], lBl[2048];
    int z = blockIdx.z;
    if (MODE == M_SCORES) { long o = (long)z * 12608; Ah += o; Al += o; Bh += o; Bl += o; }
    if (MODE == M_AV)     { long oa = (long)z * 88256, ob = (long)z * 14336;
                            Ah += oa; Al += oa; Bh += ob; Bl += ob; }
    int tid = threadIdx.x;
    int lane = tid & 63;
    int quad = lane >> 4, mr = lane & 15;
    int wave = tid >> 6;
    int wm = (wave >> 1) << 5, wn = (wave & 1) << 5;
    int tm = blockIdx.y, tn = blockIdx.x;
    int srow = tid >> 2, skq = tid & 3;
    int sdst = (((srow >> 4) << 2) + skq) * 128 + (srow & 15) * 8;
    int arow = (tm << 6) + srow, brow = (tn << 6) + srow;
    bool aval = arow < M, bval = brow < N;
    const short* aph = Ah + (long)arow * lda + (skq << 3);
    const short* apl = Al + (long)arow * lda + (skq << 3);
    const short* bph = Bh + (long)brow * ldb + (skq << 3);
    const short* bpl = Bl + (long)brow * ldb + (skq << 3);
    f4v zf = {0.f, 0.f, 0.f, 0.f};
    f4v acc00 = zf, acc01 = zf, acc10 = zf, acc11 = zf;
    int fa0 = ((wm >> 4) * 64 + lane) * 8;
    int fa1 = fa0 + 512;
    int fb0 = ((wn >> 4) * 64 + lane) * 8;
    int fb1 = fb0 + 512;
    s8v zs = {0, 0, 0, 0, 0, 0, 0, 0};
    for (int k0 = 0; k0 < K; k0 += 32) {
        s8v vah = aval ? *(const s8v*)aph : zs;
        s8v val_ = aval ? *(const s8v*)apl : zs;
        s8v vbh = bval ? *(const s8v*)bph : zs;
        s8v vbl = bval ? *(const s8v*)bpl : zs;
        aph += 32; apl += 32; bph += 32; bpl += 32;
        __syncthreads();
        *(s8v*)(lAh + sdst) = vah;
        *(s8v*)(lAl + sdst) = val_;
        *(s8v*)(lBh + sdst) = vbh;
        *(s8v*)(lBl + sdst) = vbl;
        __syncthreads();
        s8v a0h = *(const s8v*)(lAh + fa0);
        s8v a1h = *(const s8v*)(lAh + fa1);
        s8v a0l = *(const s8v*)(lAl + fa0);
        s8v a1l = *(const s8v*)(lAl + fa1);
        s8v b0h = *(const s8v*)(lBh + fb0);
        s8v b1h = *(const s8v*)(lBh + fb1);
        s8v b0l = *(const s8v*)(lBl + fb0);
        s8v b1l = *(const s8v*)(lBl + fb1);
        acc00 = __builtin_amdgcn_mfma_f32_16x16x32_bf16(a0h, b0h, acc00, 0, 0, 0);
        acc01 = __builtin_amdgcn_mfma_f32_16x16x32_bf16(a0h, b1h, acc01, 0, 0, 0);
        acc10 = __builtin_amdgcn_mfma_f32_16x16x32_bf16(a1h, b0h, acc10, 0, 0, 0);
        acc11 = __builtin_amdgcn_mfma_f32_16x16x32_bf16(a1h, b1h, acc11, 0, 0, 0);
        acc00 = __builtin_amdgcn_mfma_f32_16x16x32_bf16(a0h, b0l, acc00, 0, 0, 0);
        acc01 = __builtin_amdgcn_mfma_f32_16x16x32_bf16(a0h, b1l, acc01, 0, 0, 0);
        acc10 = __builtin_amdgcn_mfma_f32_16x16x32_bf16(a1h, b0l, acc10, 0, 0, 0);
        acc11 = __builtin_amdgcn_mfma_f32_16x16x32_bf16(a1h, b1l, acc11, 0, 0, 0);
        acc00 = __builtin_amdgcn_mfma_f32_16x16x32_bf16(a0l, b0h, acc00, 0, 0, 0);
        acc01 = __builtin_amdgcn_mfma_f32_16x16x32_bf16(a0l, b1h, acc01, 0, 0, 0);
        acc10 = __builtin_amdgcn_mfma_f32_16x16x32_bf16(a1l, b0h, acc10, 0, 0, 0);
        acc11 = __builtin_amdgcn_mfma_f32_16x16x32_bf16(a1l, b1h, acc11, 0, 0, 0);
    }
    f4v accs[2][2] = {{acc00, acc01}, {acc10, acc11}};
    #pragma unroll
    for (int mi = 0; mi < 2; mi++)
    #pragma unroll
    for (int ni = 0; ni < 2; ni++) {
        f4v ac = accs[mi][ni];
        #pragma unroll
        for (int r = 0; r < 4; r++) {
            int gm = (tm << 6) + wm + (mi << 4) + (quad << 2) + r;
            int gn = (tn << 6) + wn + (ni << 4) + mr;
            if (gm >= M || gn >= N) continue;
            float v = ac[r];
            if (MODE == M_QKV) {
                ((float*)Cv)[(long)gm * ldc + gn] = v + bias[gn];
            } else if (MODE == M_SCORES) {
                ((float*)Cv)[(long)z * 44128 + (long)gm * 224 + gn] = v * 8.f;
            } else if (MODE == M_AV) {
                int bb2 = z / 12, h = z - bb2 * 12;
                long di = (long)(bb2 * 197 + gm) * 768 + h * 64 + gn;
                __hip_bfloat16 hh, ll;
                bsplit(v, hh, ll);
                ((__hip_bfloat16*)Cv)[di] = hh;
                ((__hip_bfloat16*)Cv2)[di] = ll;
            } else if (MODE == M_BIAS_RES) {
                ((float*)Cv)[(long)gm * ldc + gn] = v + bias[gn] + resid[(long)gm * ldc + gn];
            } else if (MODE == M_FF1) {
                v = fmaxf(v + bias[gn], 0.f);
                __hip_bfloat16 hh, ll;
                bsplit(v, hh, ll);
                ((__hip_bfloat16*)Cv)[(long)gm * ldc + gn] = hh;
                ((__hip_bfloat16*)Cv2)[(long)gm * ldc + gn] = ll;
            } else if (MODE == M_HEAD) {
                ((float*)Cv)[(long)gm * ldc + gn] = v + bias[gn];
            } else if (MODE == M_EMBED) {
                v = fmaxf(v * bias[gn] + resid[gn], 0.f);  // BN scale/shift + ReLU
                int bb2 = gm / 196, p = gm - bb2 * 196;
                v += aux[(p + 1) * 768 + gn];              // pos_enc
                ((float*)Cv)[(long)(bb2 * 197 + p + 1) * 768 + gn] = v;
            }
        }
    }
}

// ---------------------------------------------------------------------------
extern "C" void kernel_launch(void* const* d_in, const int* in_sizes, int n_in,
                              void* d_out, int out_size, void* d_ws, size_t ws_size,
                              hipStream_t stream)
{
    (void)in_sizes; (void)n_in; (void)out_size; (void)ws_size;
    const float* x_in = (const float*)d_in[0];
    const float *conv_w[5], *bng[5], *bnb[5], *bnm[5], *bnv[5];
    for (int i = 0; i < 5; i++) {
        conv_w[i] = (const float*)d_in[1 + i * 5];
        bng[i]    = (const float*)d_in[2 + i * 5];
        bnb[i]    = (const float*)d_in[3 + i * 5];
        bnm[i]    = (const float*)d_in[4 + i * 5];
        bnv[i]    = (const float*)d_in[5 + i * 5];
    }
    const float* cls_token = (const float*)d_in[26];
    const float* pos_enc   = (const float*)d_in[27];
    const float* ln1_a = (const float*)d_in[28];
    const float* ln1_b = (const float*)d_in[29];
    const float* qkv_w = (const float*)d_in[30];
    const float* qkv_b = (const float*)d_in[31];
    const float* proj_w = (const float*)d_in[32];
    const float* proj_b = (const float*)d_in[33];
    const float* ln2_a = (const float*)d_in[34];
    const float* ln2_b = (const float*)d_in[35];
    const float* ff1_w = (const float*)d_in[36];
    const float* ff1_b = (const float*)d_in[37];
    const float* ff2_w = (const float*)d_in[38];
    const float* ff2_b = (const float*)d_in[39];
    const float* norm_a = (const float*)d_in[40];
    const float* norm_b = (const float*)d_in[41];
    const float* fc_w  = (const float*)d_in[42];
    const float* fc_b  = (const float*)d_in[43];

    char* ws = (char*)d_ws;
    size_t off = 0;
    auto alloc = [&](size_t bytes) {
        off = (off + 255) & ~(size_t)255;
        char* p = ws + off;
        off += bytes;
        return p;
    };
    char* arena = (char*)alloc(154140672);
    float* xbuf = (float*)alloc(19365888);                       // [32,197,768] fp32
    __hip_bfloat16* yh  = (__hip_bfloat16*)alloc(9682944);
    __hip_bfloat16* yl  = (__hip_bfloat16*)alloc(9682944);
    __hip_bfloat16* aoh = (__hip_bfloat16*)alloc(9682944);
    __hip_bfloat16* aol = (__hip_bfloat16*)alloc(9682944);
    __hip_bfloat16* wqkvh = (__hip_bfloat16*)alloc(3538944);
    __hip_bfloat16* wqkvl = (__hip_bfloat16*)alloc(3538944);
    __hip_bfloat16* wprojh = (__hip_bfloat16*)alloc(1179648);
    __hip_bfloat16* wprojl = (__hip_bfloat16*)alloc(1179648);
    __hip_bfloat16* wff1h = (__hip_bfloat16*)alloc(4718592);
    __hip_bfloat16* wff1l = (__hip_bfloat16*)alloc(4718592);
    __hip_bfloat16* wff2h = (__hip_bfloat16*)alloc(4718592);
    __hip_bfloat16* wff2l = (__hip_bfloat16*)alloc(4718592);
    __hip_bfloat16* wfch = (__hip_bfloat16*)alloc(1536000);
    __hip_bfloat16* wfcl = (__hip_bfloat16*)alloc(1536000);
    __hip_bfloat16* wc4h = (__hip_bfloat16*)alloc(786432);
    __hip_bfloat16* wc4l = (__hip_bfloat16*)alloc(786432);
    __hip_bfloat16* wc1h = (__hip_bfloat16*)alloc(147456);
    __hip_bfloat16* wc1l = (__hip_bfloat16*)alloc(147456);
    __hip_bfloat16* wc2h = (__hip_bfloat16*)alloc(589824);
    __hip_bfloat16* wc2l = (__hip_bfloat16*)alloc(589824);
    __hip_bfloat16* wc3h = (__hip_bfloat16*)alloc(2359296);
    __hip_bfloat16* wc3l = (__hip_bfloat16*)alloc(2359296);
    float* bnS0 = (float*)alloc(2048); float* bnB0 = (float*)alloc(2048);
    float* bnS1 = (float*)alloc(2048); float* bnB1 = (float*)alloc(2048);
    float* bnS2 = (float*)alloc(2048); float* bnB2 = (float*)alloc(2048);
    float* bnS3 = (float*)alloc(2048); float* bnB3 = (float*)alloc(2048);
    float* bn4s = (float*)alloc(3072); float* bn4b = (float*)alloc(3072);
    __hip_bfloat16* hlnh = (__hip_bfloat16*)alloc(49152);
    __hip_bfloat16* hlnl = (__hip_bfloat16*)alloc(49152);

    // arena lifetime map -- stem (channels-last hi/lo planes), BYTE offsets:
    // y0: 32*112*112*64 el = 51,380,224 B each plane
    short* y0h = (short*)arena;
    short* y0l = (short*)(arena + 51380224);
    // y1: 32*56*56*128 el = 25,690,112 B each plane (y0h+y0l end = 102,760,448)
    short* y1h = (short*)(arena + 102760448);
    short* y1l = (short*)(arena + 128450560);            // ends 154,140,672
    // y2: 32*28*28*256 el = 12,845,056 B each (aliases dead y0 region)
    short* y2h = (short*)arena;
    short* y2l = (short*)(arena + 12845056);             // ends 25,690,112
    // y3: 32*14*14*512 el = 6,422,528 B each
    short* y3h = (short*)(arena + 25690112);
    short* y3l = (short*)(arena + 32112640);             // ends 38,535,168
    // transformer phase:
    float* qkvf = (float*)arena;                         // qkv fp32 (58.1 MB)
    float* Sbuf = (float*)arena;                         // scores fp32 (67.78 MB)
    __hip_bfloat16* qh = (__hip_bfloat16*)(arena + 67780608);
    __hip_bfloat16* ql = (__hip_bfloat16*)(arena + 77463552);
    __hip_bfloat16* kh = (__hip_bfloat16*)(arena + 87146496);
    __hip_bfloat16* kl = (__hip_bfloat16*)(arena + 96829440);
    __hip_bfloat16* vTh = (__hip_bfloat16*)(arena + 106512384);
    __hip_bfloat16* vTl = (__hip_bfloat16*)(arena + 117522432);
    __hip_bfloat16* hffh = (__hip_bfloat16*)arena;                 // 38.73 MB
    __hip_bfloat16* hffl = (__hip_bfloat16*)(arena + 38731776);    // 38.73 MB

    // ---- conv weight prep + BN folding ----
    repack_cw<<<dim3(288), 256, 0, stream>>>(conv_w[1], wc1h, wc1l, 64, 6, 576, 73728);
    repack_cw<<<dim3(1152), 256, 0, stream>>>(conv_w[2], wc2h, wc2l, 128, 7, 1152, 294912);
    repack_cw<<<dim3(4608), 256, 0, stream>>>(conv_w[3], wc3h, wc3l, 256, 8, 2304, 1179648);
    bn_prep<<<dim3(1), 256, 0, stream>>>(bng[0], bnb[0], bnm[0], bnv[0], bnS0, bnB0, 64);
    bn_prep<<<dim3(1), 256, 0, stream>>>(bng[1], bnb[1], bnm[1], bnv[1], bnS1, bnB1, 128);
    bn_prep<<<dim3(1), 256, 0, stream>>>(bng[2], bnb[2], bnm[2], bnv[2], bnS2, bnB2, 256);
    bn_prep<<<dim3(2), 256, 0, stream>>>(bng[3], bnb[3], bnm[3], bnv[3], bnS3, bnB3, 512);
    bn_prep<<<dim3(3), 256, 0, stream>>>(bng[4], bnb[4], bnm[4], bnv[4], bn4s, bn4b, 768);
    f32_split_k<<<dim3(1536), 256, 0, stream>>>(conv_w[4], wc4h, wc4l, 393216);

    // ---- conv stem (implicit-GEMM MFMA, channels-last) ----
    conv0_k<<<dim3(7, 7, 32), 256, 0, stream>>>(x_in, conv_w[0], bnS0, bnB0, y0h, y0l);
    conv_gemm<<<dim3(2, 1568), 256, 0, stream>>>(
        y0h, y0l, (const short*)wc1h, (const short*)wc1l, bnS1, bnB1, y1h, y1l,
        112, 112, 56, 56, 6, 128, 576);
    conv_gemm<<<dim3(4, 392), 256, 0, stream>>>(
        y1h, y1l, (const short*)wc2h, (const short*)wc2l, bnS2, bnB2, y2h, y2l,
        56, 56, 28, 28, 7, 256, 1152);
    conv_gemm<<<dim3(8, 98), 256, 0, stream>>>(
        y2h, y2l, (const short*)wc3h, (const short*)wc3l, bnS3, bnB3, y3h, y3l,
        28, 28, 14, 14, 8, 512, 2304);

    // ---- conv4 (1x1) as split GEMM + embed ----
    cls_embed<<<dim3(96), 256, 0, stream>>>(cls_token, pos_enc, xbuf);
    gemm_bt<M_EMBED><<<dim3(12, 98, 1), 256, 0, stream>>>(
        y3h, y3l, (const short*)wc4h, (const short*)wc4l,
        bn4s, bn4b, pos_enc, xbuf, nullptr, 6272, 768, 512, 512, 512, 768);

    // ---- 12 transformer layers ----
    for (int l = 0; l < 12; l++) {
        transpose_split<<<dim3(72, 24, 1), 256, 0, stream>>>(
            qkv_w + (long)l * 768 * 2304, wqkvh, wqkvl, 768, 2304);
        transpose_split<<<dim3(24, 24, 1), 256, 0, stream>>>(
            proj_w + (long)l * 768 * 768, wprojh, wprojl, 768, 768);
        transpose_split<<<dim3(96, 24, 1), 256, 0, stream>>>(
            ff1_w + (long)l * 768 * 3072, wff1h, wff1l, 768, 3072);
        transpose_split<<<dim3(24, 96, 1), 256, 0, stream>>>(
            ff2_w + (long)l * 3072 * 768, wff2h, wff2l, 3072, 768);

        ln_fwd<<<dim3(6304), 256, 0, stream>>>(
            xbuf, 768L, ln1_a + l * 768, ln1_b + l * 768, yh, yl, 6304);
        gemm_bt<M_QKV><<<dim3(36, 99, 1), 256, 0, stream>>>(
            (const short*)yh, (const short*)yl, (const short*)wqkvh, (const short*)wqkvl,
            qkv_b + l * 2304, nullptr, nullptr, qkvf, nullptr,
            6304, 2304, 768, 768, 768, 2304);
        repack_qk_f<<<dim3(37824), 256, 0, stream>>>(qkvf, qh, ql, kh, kl);
        repack_v_f<<<dim3(4, 384), 256, 0, stream>>>(qkvf, vTh, vTl);
        gemm_bt<M_SCORES><<<dim3(4, 4, 384), 256, 0, stream>>>(
            (const short*)qh, (const short*)ql, (const short*)kh, (const short*)kl,
            nullptr, nullptr, nullptr, Sbuf, nullptr, 197, 197, 64, 64, 64, 224);
        softmax_k<<<dim3(18912), 256, 0, stream>>>(Sbuf, 75648);
        gemm_bt<M_AV><<<dim3(1, 4, 384), 256, 0, stream>>>(
            (const short*)Sbuf, (const short*)Sbuf + 224, (const short*)vTh, (const short*)vTl,
            nullptr, nullptr, nullptr, aoh, aol, 197, 64, 224, 448, 224, 768);
        gemm_bt<M_BIAS_RES><<<dim3(12, 99, 1), 256, 0, stream>>>(
            (const short*)aoh, (const short*)aol, (const short*)wprojh, (const short*)wprojl,
            proj_b + l * 768, xbuf, nullptr, xbuf, nullptr,
            6304, 768, 768, 768, 768, 768);
        ln_fwd<<<dim3(6304), 256, 0, stream>>>(
            xbuf, 768L, ln2_a + l * 768, ln2_b + l * 768, yh, yl, 6304);
        gemm_bt<M_FF1><<<dim3(48, 99, 1), 256, 0, stream>>>(
            (const short*)yh, (const short*)yl, (const short*)wff1h, (const short*)wff1l,
            ff1_b + l * 3072, nullptr, nullptr, hffh, hffl,
            6304, 3072, 768, 768, 768, 3072);
        gemm_bt<M_BIAS_RES><<<dim3(12, 99, 1), 256, 0, stream>>>(
            (const short*)hffh, (const short*)hffl, (const short*)wff2h, (const short*)wff2l,
            ff2_b + l * 768, xbuf, nullptr, xbuf, nullptr,
            6304, 768, 3072, 3072, 3072, 768);
    }

    // ---- head ----
    transpose_split<<<dim3(32, 24, 1), 256, 0, stream>>>(fc_w, wfch, wfcl, 768, 1000);
    ln_fwd<<<dim3(32), 256, 0, stream>>>(xbuf, 197L * 768L, norm_a, norm_b, hlnh, hlnl, 32);
    gemm_bt<M_HEAD><<<dim3(16, 1, 1), 256, 0, stream>>>(
        (const short*)hlnh, (const short*)hlnl, (const short*)wfch, (const short*)wfcl,
        fc_b, nullptr, nullptr, d_out, nullptr, 32, 1000, 768, 768, 768, 1000);
}